// Round 15
// baseline (207.181 us; speedup 1.0000x reference)
//
#include <hip/hip_runtime.h>
#include <math.h>

// Problem constants
#define B_     16
#define CIN_   128
#define NTOK_  640     // channels after concat = tokens
#define PSP_   256     // 16*16 spatial = token dim
#define EMB_   256
#define HEADS_ 8
#define DH_    32
#define BH_    128     // B_*HEADS_
#define NH_    8       // hashes
#define NBK_   10      // buckets per hash (t/BUCKET)
#define NC_    80      // chunks = NH_*NBK_
#define TOTROWS_ 10240 // B_*NTOK_
#define SORTLEN_ 5120  // NH_*NTOK_
#define VSTRIDE 136    // sVT row stride in shorts (272B: breaks the 256B bank period)

typedef __attribute__((ext_vector_type(8))) short short8;
typedef __attribute__((ext_vector_type(4))) short short4v;
typedef __attribute__((ext_vector_type(4))) float f32x4;

__device__ __forceinline__ unsigned bf16r(float f) {
  // round-to-nearest (half-up) fp32 -> bf16 bits
  return (__float_as_uint(f) + 0x8000u) >> 16;
}

__device__ __forceinline__ unsigned cvt_pk_bf16(float a, float b) {
  // packed fp32 -> 2x bf16 (lo = a, hi = b), RNE
  unsigned r;
  asm("v_cvt_pk_bf16_f32 %0, %1, %2" : "=v"(r) : "v"(a), "v"(b));
  return r;
}

// ---------------------------------------------------------------------------
// Kernel 1: maxpool(3,s2,p1) + Haar DWT -> tokens (B, 640, 256)
// + fused weight transpose/bf16 prep (blocks 0..255): wtv, wto
// ---------------------------------------------------------------------------
__global__ __launch_bounds__(256) void k_tokens(const float* __restrict__ x,
                                                float* __restrict__ tok,
                                                const float* __restrict__ wv,
                                                const float* __restrict__ wo,
                                                unsigned short* __restrict__ wtv,
                                                unsigned short* __restrict__ wto) {
  if (blockIdx.x < 256) {                       // fused k_prep
    int idx = blockIdx.x * 256 + threadIdx.x;   // 65536
    int n = idx >> 8, k = idx & 255;
    wtv[idx] = (unsigned short)bf16r(wv[k * 256 + n]);
    wto[idx] = (unsigned short)bf16r(wo[k * 256 + n]);
  }
  int tid = blockIdx.x * 256 + threadIdx.x;     // [0, 16*128*256)
  int p  = tid & 255;
  int bc = tid >> 8;                            // b*128 + c
  int i = p >> 4, j = p & 15;
  const float* xp = x + (size_t)bc * 1024;      // 32*32 plane
  int r0 = i * 2, c0 = j * 2;

  float mx = -3.4e38f;
  #pragma unroll
  for (int dr = -1; dr <= 1; dr++) {
    int r = r0 + dr;
    if (r < 0 || r >= 32) continue;
    #pragma unroll
    for (int dc = -1; dc <= 1; dc++) {
      int cc = c0 + dc;
      if (cc < 0 || cc >= 32) continue;
      mx = fmaxf(mx, xp[r * 32 + cc]);
    }
  }
  float a  = xp[r0 * 32 + c0];
  float bv = xp[r0 * 32 + c0 + 1];
  float cv = xp[(r0 + 1) * 32 + c0];
  float dv = xp[(r0 + 1) * 32 + c0 + 1];
  float ll = (a + bv + cv + dv) * 0.5f;
  float lh = (a - bv + cv - dv) * 0.5f;
  float hl = (a + bv - cv - dv) * 0.5f;
  float hh = (a - bv - cv + dv) * 0.5f;

  int b = bc >> 7, c = bc & 127;
  float* tb = tok + (size_t)b * NTOK_ * PSP_ + p;
  tb[(size_t)(c      ) * PSP_] = mx;
  tb[(size_t)(c + 128) * PSP_] = ll;
  tb[(size_t)(c + 256) * PSP_] = lh;
  tb[(size_t)(c + 384) * PSP_] = hl;
  tb[(size_t)(c + 512) * PSP_] = hh;
}

// ---------------------------------------------------------------------------
// Kernel 2: MERGED GEMM. Blocks 0..639: fp32 qk (argmax needs fp32) with
// dual fp32+bf16 output, 64x64 tile, BK=64. Blocks 640..959: bf16 MFMA
// v-GEMM (64 rows x 128 cols, 4 waves), bf16 output.
// ---------------------------------------------------------------------------
__global__ __launch_bounds__(256) void k_gemm_qv(const float* __restrict__ A,
                                                 const float* __restrict__ Wq,
                                                 const unsigned short* __restrict__ WTv,
                                                 float* __restrict__ C,
                                                 unsigned short* __restrict__ Cb,
                                                 unsigned short* __restrict__ Cv) {
  __shared__ float As[64][68];    // [k][row], padded +4
  __shared__ float Bs[64][64];    // [k][col]
  int tid = threadIdx.x;

  if (blockIdx.x < 640) {
    // ---------------- fp32 qk path ----------------
    int bx = blockIdx.x;
    int row0 = (bx >> 2) * 64, col0 = (bx & 3) * 64;
    int tx = tid & 15, ty = tid >> 4;
    float acc[4][4] = {};

    int lrow = tid >> 2, lkq = tid & 3;        // A loader
    int bkr = tid >> 4, bcq = tid & 15;        // B loader

    for (int k0 = 0; k0 < 256; k0 += 64) {
      float4 va[4], vb4[4];
      #pragma unroll
      for (int i = 0; i < 4; i++) {
        va[i]  = *(const float4*)(&A[(size_t)(row0 + lrow) * 256 + k0 + i * 16 + 4 * lkq]);
        vb4[i] = *(const float4*)(&Wq[(size_t)(k0 + i * 16 + bkr) * 256 + col0 + 4 * bcq]);
      }
      __syncthreads();
      #pragma unroll
      for (int i = 0; i < 4; i++) {
        As[i * 16 + 4 * lkq + 0][lrow] = va[i].x;
        As[i * 16 + 4 * lkq + 1][lrow] = va[i].y;
        As[i * 16 + 4 * lkq + 2][lrow] = va[i].z;
        As[i * 16 + 4 * lkq + 3][lrow] = va[i].w;
        *(float4*)(&Bs[i * 16 + bkr][4 * bcq]) = vb4[i];
      }
      __syncthreads();
      #pragma unroll
      for (int k = 0; k < 64; k++) {
        const float4 b4 = *(const float4*)(&Bs[k][4 * tx]);
        const float4 a4 = *(const float4*)(&As[k][4 * ty]);
        float ar[4] = {a4.x, a4.y, a4.z, a4.w};
        #pragma unroll
        for (int r = 0; r < 4; r++) {
          acc[r][0] += ar[r] * b4.x; acc[r][1] += ar[r] * b4.y;
          acc[r][2] += ar[r] * b4.z; acc[r][3] += ar[r] * b4.w;
        }
      }
    }
    #pragma unroll
    for (int r = 0; r < 4; r++) {
      float4 o;
      o.x = acc[r][0]; o.y = acc[r][1]; o.z = acc[r][2]; o.w = acc[r][3];
      size_t off = (size_t)(row0 + 4 * ty + r) * 256 + col0 + 4 * tx;
      *(float4*)(&C[off]) = o;
      uint2 ub;
      ub.x = bf16r(o.x) | (bf16r(o.y) << 16);
      ub.y = bf16r(o.z) | (bf16r(o.w) << 16);
      *(uint2*)(&Cb[off]) = ub;
    }
  } else {
    // ---------------- bf16 MFMA v path ----------------
    int vbk = blockIdx.x - 640;                // 0..319
    int wid = tid >> 6, lane = tid & 63;
    int lane15 = lane & 15, quad = lane >> 4;
    int row0 = (vbk >> 1) * 64 + wid * 16;
    int col0 = (vbk & 1) * 128;

    short8 fa[8];
    const float* arow = A + (size_t)(row0 + lane15) * 256;
    #pragma unroll
    for (int kc = 0; kc < 8; kc++) {
      float4 x0 = *(const float4*)(arow + kc * 32 + quad * 8);
      float4 x1 = *(const float4*)(arow + kc * 32 + quad * 8 + 4);
      short8 f;
      f[0] = (short)bf16r(x0.x); f[1] = (short)bf16r(x0.y);
      f[2] = (short)bf16r(x0.z); f[3] = (short)bf16r(x0.w);
      f[4] = (short)bf16r(x1.x); f[5] = (short)bf16r(x1.y);
      f[6] = (short)bf16r(x1.z); f[7] = (short)bf16r(x1.w);
      fa[kc] = f;
    }
    #pragma unroll
    for (int nt = 0; nt < 8; nt++) {
      int col = col0 + nt * 16 + lane15;
      f32x4 acc = {0.f, 0.f, 0.f, 0.f};
      const unsigned short* wrow = WTv + (size_t)col * 256;
      #pragma unroll
      for (int kc = 0; kc < 8; kc++) {
        short8 fb = *(const short8*)(wrow + kc * 32 + quad * 8);
        acc = __builtin_amdgcn_mfma_f32_16x16x32_bf16(fa[kc], fb, acc, 0, 0, 0);
      }
      #pragma unroll
      for (int rg = 0; rg < 4; rg++)
        Cv[(size_t)(row0 + 4 * quad + rg) * 256 + col] = (unsigned short)bf16r(acc[rg]);
    }
  }
}

// ---------------------------------------------------------------------------
// Kernel 3: LSH bucket + stable counting sort.
// XCD-SWIZZLED grid (128 bh, 8 hashes): bh = blockIdx.x so all 8 hash-blocks
// of one bh land on XCD bh%8 -> shared qk slice stays L2-resident.
// h==0 blocks additionally write nrmv[bh][t] = |qk row| (fp32) for k_attn.
// ---------------------------------------------------------------------------
__global__ __launch_bounds__(640) void k_sort(const float* __restrict__ qkg,
                                              const float* __restrict__ rot,
                                              int* __restrict__ st,
                                              float* __restrict__ nrmv) {
  int bh = blockIdx.x, h = blockIdx.y;
  int b = bh >> 3, head = bh & 7;
  __shared__ float srot[5][32];
  __shared__ int wcnt[10][10];   // [wave][bucket]
  __shared__ int woff[10][10];   // exclusive prefix over waves, per bucket
  __shared__ int gbase[10];      // exclusive prefix over buckets
  int tid = threadIdx.x, wv = tid >> 6, ln = tid & 63;

  if (tid < 160) {
    int i = tid >> 5, f = tid & 31;
    srot[i][f] = rot[f * (NH_ * 5) + h * 5 + i];   // rotations (32, 8, 5)
  }
  __syncthreads();

  int t = tid;                                     // one token per thread
  const float* qr = qkg + ((size_t)b * NTOK_ + t) * EMB_ + head * DH_;
  float q[32];
  #pragma unroll
  for (int d4 = 0; d4 < 8; d4++) {
    float4 f = *(const float4*)(qr + d4 * 4);
    q[d4 * 4 + 0] = f.x; q[d4 * 4 + 1] = f.y; q[d4 * 4 + 2] = f.z; q[d4 * 4 + 3] = f.w;
  }
  if (h == 0) {                                    // norm precompute for k_attn
    float d2 = 0.f;
    #pragma unroll
    for (int dd = 0; dd < 32; dd++) d2 += q[dd] * q[dd];
    nrmv[(size_t)bh * NTOK_ + t] = sqrtf(d2);
  }
  float r[5];
  #pragma unroll
  for (int i = 0; i < 5; i++) {
    float d = 0.f;
    #pragma unroll
    for (int dd = 0; dd < 32; dd++) d += q[dd] * srot[i][dd];
    r[i] = d;
  }
  int bi = 0; float best = r[0];
  #pragma unroll
  for (int i = 1; i < 5; i++) if (r[i] > best) { best = r[i]; bi = i; }
  #pragma unroll
  for (int i = 0; i < 5; i++) if (-r[i] > best) { best = -r[i]; bi = 5 + i; }

  // per-wave histogram + intra-wave stable rank via ballot
  int myoff = 0;
  #pragma unroll
  for (int kb = 0; kb < 10; kb++) {
    unsigned long long mask = __ballot(bi == kb);
    if (ln == 0) wcnt[wv][kb] = (int)__popcll(mask);
    if (bi == kb) myoff = (int)__popcll(mask & ((1ull << ln) - 1ull));
  }
  __syncthreads();
  if (tid < 10) {                                  // bucket = tid: scan over 10 waves
    int run = 0;
    #pragma unroll
    for (int w2 = 0; w2 < 10; w2++) { int tmp = wcnt[w2][tid]; woff[w2][tid] = run; run += tmp; }
    gbase[tid] = run;
  }
  __syncthreads();
  if (tid == 0) {
    int run = 0;
    #pragma unroll
    for (int kb = 0; kb < 10; kb++) { int tmp = gbase[kb]; gbase[kb] = run; run += tmp; }
  }
  __syncthreads();
  int rank = gbase[bi] + woff[wv][bi] + myoff;
  size_t gb = (size_t)bh * SORTLEN_ + (size_t)h * 640;
  st[gb + rank] = t;
}

// ---------------------------------------------------------------------------
// Kernel 4: MFMA chunked attention — CHUNK-CHAINED. grid (128 bh, 8 rounds).
// One block walks its hash round's 10 chunks with double-buffered LDS halves:
// each iteration stages only the 64 NEW rows (current chunk); the previous
// chunk is already resident -> staging 1280 -> 704 rows per (bh,h) (-45%).
// 4 lanes per slot: 1 uint4 K + 1 uint4 V per lane. cur/prv are compile-time
// via a 2-body rolled loop. Per-chunk math identical to the R14 kernel.
// ---------------------------------------------------------------------------
__global__ __launch_bounds__(256) void k_attn(const unsigned short* __restrict__ qkb,
                                              const unsigned short* __restrict__ vb,
                                              const int* __restrict__ st,
                                              const float* __restrict__ nrmv,
                                              unsigned short* __restrict__ osort,
                                              float* __restrict__ lseg) {
  __shared__ __attribute__((aligned(16))) short sK[4096];          // 2 halves x 64 rows x 32 bf16, pair-row swizzled
  __shared__ __attribute__((aligned(16))) short sVT[32 * VSTRIDE]; // 32 feats x (2 halves x 64 key-slots, PERMUTED)
  __shared__ __attribute__((aligned(16))) short sP[2048];          // 64x32 dense output staging
  __shared__ float sM[64];    // |q|*scale per current-chunk query row
  __shared__ float sIK[128];  // [half*64 + slot] key scale
  __shared__ float sL[64];    // row softmax denominators
  __shared__ int   stkv[128]; // [half*64 + slot] token ids

  const float scale = 0.17677669529663687f;   // 1/sqrt(32)
  const float LOG2E = 1.4426950408889634f;
  const float K2 = scale * LOG2E;
  int bh = blockIdx.x, h = blockIdx.y;
  int b = bh >> 3, head = bh & 7;
  int lane = threadIdx.x & 63, wid = threadIdx.x >> 6;   // wid 0..3
  int lane15 = lane & 15, quad = lane >> 4;
  size_t stb = (size_t)bh * SORTLEN_;

  int slot4 = threadIdx.x >> 2;              // 0..63: kv slot
  int qf    = threadIdx.x & 3;               // quarter of the row
  int qd    = 16 * wid + lane15 - 4 * quad;  // diag test for current-chunk strips

  // stage 64 rows of chunk CC into half HB (4 lanes per slot)
#define STAGE(CC, HB, WRM)                                                    \
  {                                                                           \
    int t0 = st[stb + (CC) * 64 + slot4];                                     \
    size_t rowoff = ((size_t)(b * NTOK_ + t0)) * EMB_ + head * DH_;           \
    uint4 kq = ((const uint4*)(qkb + rowoff))[qf];                            \
    int gs = (HB) * 64 + slot4;                                               \
    int pr = gs >> 1;                                                         \
    int blk = ((gs & 1) << 2) | qf;                                           \
    *(uint4*)(&sK[pr * 64 + ((blk ^ (pr & 7)) << 3)]) = kq;                   \
    uint4 vq = ((const uint4*)(vb + rowoff))[qf];                             \
    int vloc = (slot4 & 32) | (((slot4 & 15) >> 2) << 3)                      \
             | (((slot4 >> 4) & 1) << 2) | (slot4 & 3);                       \
    short* vbase = &sVT[(qf * 8) * VSTRIDE + (HB) * 64 + vloc];               \
    vbase[0 * VSTRIDE] = (short)(vq.x & 0xFFFFu);                             \
    vbase[1 * VSTRIDE] = (short)(vq.x >> 16);                                 \
    vbase[2 * VSTRIDE] = (short)(vq.y & 0xFFFFu);                             \
    vbase[3 * VSTRIDE] = (short)(vq.y >> 16);                                 \
    vbase[4 * VSTRIDE] = (short)(vq.z & 0xFFFFu);                             \
    vbase[5 * VSTRIDE] = (short)(vq.z >> 16);                                 \
    vbase[6 * VSTRIDE] = (short)(vq.w & 0xFFFFu);                             \
    vbase[7 * VSTRIDE] = (short)(vq.w >> 16);                                 \
    if (qf == 0) {                                                            \
      stkv[gs] = t0;                                                          \
      float nr = nrmv[(size_t)bh * NTOK_ + t0];                               \
      sIK[gs] = K2 / fmaxf(nr, 1e-6f);                                        \
      if (WRM) sM[slot4] = nr * scale;                                        \
    }                                                                         \
  }

  // process chunk CI of this round; current half CUR, previous half PRV
#define BODY(CI, CUR, PRV)                                                    \
  {                                                                           \
    STAGE(h * NBK_ + (CI), CUR, 1);                                           \
    __syncthreads();                                                          \
    short8 fall[8];                                                           \
    _Pragma("unroll")                                                         \
    for (int ii = 0; ii < 8; ii++) {                                          \
      int hb = (ii < 4) ? (CUR) : (PRV);                                      \
      int gs = hb * 64 + 16 * (ii & 3) + lane15;                              \
      int pr = gs >> 1, blk = ((gs & 1) << 2) | quad;                         \
      fall[ii] = *(const short8*)(&sK[pr * 64 + ((blk ^ (pr & 7)) << 3)]);    \
    }                                                                         \
    short8 fq;                                                                \
    { int gs = (CUR) * 64 + 16 * wid + lane15;                                \
      int pr = gs >> 1, blk = ((gs & 1) << 2) | quad;                         \
      fq = *(const short8*)(&sK[pr * 64 + ((blk ^ (pr & 7)) << 3)]); }        \
    int   tq  = stkv[(CUR) * 64 + 16 * wid + lane15];                         \
    float mq  = sM[16 * wid + lane15];                                        \
    float mq2 = mq * LOG2E;                                                   \
    f32x4 O[2];                                                               \
    O[0][0]=0.f; O[0][1]=0.f; O[0][2]=0.f; O[0][3]=0.f;                       \
    O[1][0]=0.f; O[1][1]=0.f; O[1][2]=0.f; O[1][3]=0.f;                       \
    float lacc = 0.f;                                                         \
    _Pragma("unroll")                                                         \
    for (int s = 0; s < 4; s++) {                                             \
      int hb = (s < 2) ? (CUR) : (PRV);                                       \
      int cb = hb * 64 + 32 * (s & 1);                                        \
      f32x4 z = {0.f, 0.f, 0.f, 0.f};                                         \
      f32x4 Sv[2];                                                            \
      _Pragma("unroll")                                                       \
      for (int ct = 0; ct < 2; ct++)                                          \
        Sv[ct] = __builtin_amdgcn_mfma_f32_16x16x32_bf16(fall[2*s+ct], fq, z, 0, 0, 0); \
      unsigned pk[2][2];                                                      \
      _Pragma("unroll")                                                       \
      for (int ct = 0; ct < 2; ct++) {                                        \
        const float4 c4 = *(const float4*)(&sIK[cb + 16 * ct + 4 * quad]);    \
        float cc[4] = {c4.x, c4.y, c4.z, c4.w};                               \
        int kk[4];                                                            \
        if (s >= 2) {                                                         \
          const int4 k4 = *(const int4*)(&stkv[cb + 16 * ct + 4 * quad]);     \
          kk[0] = k4.x; kk[1] = k4.y; kk[2] = k4.z; kk[3] = k4.w;             \
        }                                                                     \
        float e[4];                                                           \
        _Pragma("unroll")                                                     \
        for (int rg = 0; rg < 4; rg++) {                                      \
          float v = __builtin_exp2f(__builtin_fmaf(Sv[ct][rg], cc[rg], -mq2)); \
          if (s < 2) {                                                        \
            if (qd == 32 * s + 16 * ct + rg) v = 0.f;                         \
          } else {                                                            \
            if (kk[rg] == tq) v = 0.f;                                        \
          }                                                                   \
          lacc += v;                                                          \
          e[rg] = v;                                                          \
        }                                                                     \
        pk[ct][0] = cvt_pk_bf16(e[0], e[1]);                                  \
        pk[ct][1] = cvt_pk_bf16(e[2], e[3]);                                  \
      }                                                                       \
      short8 fp;                                                              \
      { union { unsigned u[4]; short8 v; } cv_;                               \
        cv_.u[0] = pk[0][0]; cv_.u[1] = pk[0][1];                             \
        cv_.u[2] = pk[1][0]; cv_.u[3] = pk[1][1];                             \
        fp = cv_.v; }                                                         \
      short8 fv[2];                                                           \
      _Pragma("unroll")                                                       \
      for (int vt = 0; vt < 2; vt++)                                          \
        fv[vt] = *(const short8*)(&sVT[(16 * vt + lane15) * VSTRIDE + cb + (quad << 3)]); \
      _Pragma("unroll")                                                       \
      for (int vt = 0; vt < 2; vt++)                                          \
        O[vt] = __builtin_amdgcn_mfma_f32_16x16x32_bf16(fp, fv[vt], O[vt], 0, 0, 0); \
    }                                                                         \
    lacc += __shfl_xor(lacc, 16);                                             \
    lacc += __shfl_xor(lacc, 32);                                             \
    if (lane < 16) {                                                          \
      sL[16 * wid + lane] = lacc;                                             \
      lseg[((size_t)bh * NTOK_ + tq) * NH_ + h] = mq + __logf(lacc);          \
    }                                                                         \
    float4 lr = *(const float4*)(&sL[16 * wid + 4 * quad]);                   \
    float lrow[4] = {lr.x, lr.y, lr.z, lr.w};                                 \
    _Pragma("unroll")                                                         \
    for (int rg = 0; rg < 4; rg++) {                                          \
      float invl = 1.f / lrow[rg];                                            \
      _Pragma("unroll")                                                       \
      for (int vt = 0; vt < 2; vt++) {                                        \
        float o = O[vt][rg] * invl;                                           \
        sP[(16 * wid + 4 * quad + rg) * 32 + 16 * vt + lane15] = (short)bf16r(o); \
      }                                                                       \
    }                                                                         \
    __syncthreads();                                                          \
    { int row = threadIdx.x >> 2, seg = threadIdx.x & 3;                      \
      int t = stkv[(CUR) * 64 + row];                                         \
      uint4* dst = (uint4*)(osort + (((size_t)bh * NTOK_ + t) * NH_ + h) * 32 + seg * 8); \
      *dst = ((const uint4*)sP)[threadIdx.x]; }                               \
  }

  // prologue: stage the chunk before this round (prev round's last) into half 1
  int pro = (h * NBK_ + NC_ - 1) % NC_;
  STAGE(pro, 1, 0);

  for (int i2 = 0; i2 < NBK_ / 2; i2++) {
    BODY(2 * i2,     0, 1);
    BODY(2 * i2 + 1, 1, 0);
  }
#undef BODY
#undef STAGE
}

// ---------------------------------------------------------------------------
// Kernel 5a: combine 8 hash rounds -> cmb[b*640+t][256] bf16.
// grid 1280 x 256: 4 threads per (bh,t), each handles 8 features (1 uint4/h).
// ---------------------------------------------------------------------------
__global__ __launch_bounds__(256) void k_combine(const unsigned short* __restrict__ osort,
                                                 const float* __restrict__ lseg,
                                                 unsigned short* __restrict__ cmb) {
  int g = blockIdx.x * 256 + threadIdx.x;      // 327,680 = 81,920 tasks x 4
  int part = g & 3;
  int task = g >> 2;                           // bh*640 + t
  int bh = task / 640;
  int t  = task - bh * 640;
  size_t base = (size_t)task;

  float l[8];
  float4 l0 = *(const float4*)(lseg + base * 8);
  float4 l1 = *(const float4*)(lseg + base * 8 + 4);
  l[0]=l0.x; l[1]=l0.y; l[2]=l0.z; l[3]=l0.w;
  l[4]=l1.x; l[5]=l1.y; l[6]=l1.z; l[7]=l1.w;
  float m = -3.4e38f;
  #pragma unroll
  for (int h = 0; h < 8; h++) m = fmaxf(m, l[h]);
  float ssum = 0.f;
  #pragma unroll
  for (int h = 0; h < 8; h++) { l[h] = __expf(l[h] - m); ssum += l[h]; }
  float inv = 1.0f / ssum;

  float acc[8] = {};
  const uint4* orows = (const uint4*)osort;
  size_t obase = base * 32 + part;             // uint4 index: (base*8+h)*4 + part
  #pragma unroll
  for (int h = 0; h < 8; h++) {
    float w = l[h] * inv;
    uint4 u = orows[obase + h * 4];
    unsigned uu[4] = {u.x, u.y, u.z, u.w};
    #pragma unroll
    for (int q2 = 0; q2 < 4; q2++) {
      float lo = __uint_as_float(uu[q2] << 16);
      float hi = __uint_as_float(uu[q2] & 0xFFFF0000u);
      acc[q2 * 2 + 0] += w * lo;
      acc[q2 * 2 + 1] += w * hi;
    }
  }
  int b = bh >> 3, head = bh & 7;
  uint4 o;
  o.x = bf16r(acc[0]) | (bf16r(acc[1]) << 16);
  o.y = bf16r(acc[2]) | (bf16r(acc[3]) << 16);
  o.z = bf16r(acc[4]) | (bf16r(acc[5]) << 16);
  o.w = bf16r(acc[6]) | (bf16r(acc[7]) << 16);
  *(uint4*)(cmb + ((size_t)(b * NTOK_ + t)) * 256 + head * 32 + part * 8) = o;
}

// ---------------------------------------------------------------------------
// Kernel 5b: output projection, pure bf16 MFMA GEMM 10240x256x256 + bias.
// grid 640: 16-row tiles; 4 waves = 4 col-quarters of 64. No LDS.
// ---------------------------------------------------------------------------
__global__ __launch_bounds__(256) void k_oproj(const unsigned short* __restrict__ cmb,
                                               const unsigned short* __restrict__ WT,
                                               const float* __restrict__ bias,
                                               float* __restrict__ C) {
  int rt = blockIdx.x;                         // 0..639: rows rt*16..+15
  int tid = threadIdx.x;
  int wid = tid >> 6, lane = tid & 63;
  int lane15 = lane & 15, quad = lane >> 4;
  int row0 = rt * 16;
  int col0 = wid * 64;

  short8 fa[8];
  const unsigned short* arow = cmb + (size_t)(row0 + lane15) * 256;
  #pragma unroll
  for (int kc = 0; kc < 8; kc++)
    fa[kc] = *(const short8*)(arow + kc * 32 + quad * 8);
  #pragma unroll
  for (int nt = 0; nt < 4; nt++) {
    int col = col0 + nt * 16 + lane15;
    f32x4 acc = {0.f, 0.f, 0.f, 0.f};
    const unsigned short* wrow = WT + (size_t)col * 256;
    #pragma unroll
    for (int kc = 0; kc < 8; kc++) {
      short8 fb = *(const short8*)(wrow + kc * 32 + quad * 8);
      acc = __builtin_amdgcn_mfma_f32_16x16x32_bf16(fa[kc], fb, acc, 0, 0, 0);
    }
    float bb = bias[col];
    #pragma unroll
    for (int rg = 0; rg < 4; rg++)
      C[(size_t)(row0 + 4 * quad + rg) * 256 + col] = acc[rg] + bb;
  }
}

// ---------------------------------------------------------------------------
extern "C" void kernel_launch(void* const* d_in, const int* in_sizes, int n_in,
                              void* d_out, int out_size, void* d_ws, size_t ws_size,
                              hipStream_t stream) {
  const float* x     = (const float*)d_in[0];
  const float* w_qk  = (const float*)d_in[1];
  const float* w_v   = (const float*)d_in[2];
  const float* w_out = (const float*)d_in[3];
  const float* b_out = (const float*)d_in[4];
  const float* rot   = (const float*)d_in[5];
  float* out = (float*)d_out;

  // workspace layout (float units)
  float* tokens  = (float*)d_ws;                      // 2,621,440 f
  float* qk      = tokens + 2621440;                  // 2,621,440 f
  unsigned short* qkb = (unsigned short*)(qk + 2621440); // 2,621,440 bf16
  unsigned short* vbv = qkb + 2621440;                // 2,621,440 bf16
  int*   st      = (int*)(vbv + 2621440);             // 655,360
  float* lse     = (float*)(st + 655360);             // 655,360  [bh][t][h]
  unsigned short* osort = (unsigned short*)(lse + 655360);  // 20,971,520 bf16 [bh][t][h][32]
  unsigned short* wtv = osort + 20971520;             // 65,536 bf16 (W_v^T)
  unsigned short* wto = wtv + 65536;                  // 65,536 bf16 (W_out^T)
  // nrmv (81,920 f) aliases tokens (dead after k_gemm_qv).
  float* nrmv = tokens;
  // cmb (2,621,440 bf16 = 5.2 MB) aliases qk (dead after k_sort).
  unsigned short* cmb = (unsigned short*)qk;

  k_tokens<<<2048, 256, 0, stream>>>(x, tokens, w_v, w_out, wtv, wto);
  k_gemm_qv<<<960, 256, 0, stream>>>(tokens, w_qk, wtv, qk, qkb, vbv);
  k_sort<<<dim3(128, 8), 640, 0, stream>>>(qk, rot, st, nrmv);          // bh-major: XCD locality
  k_attn<<<dim3(128, 8), 256, 0, stream>>>(qkb, vbv, st, nrmv, osort, lse); // chunk-chained rounds
  k_combine<<<1280, 256, 0, stream>>>(osort, lse, cmb);
  k_oproj<<<640, 256, 0, stream>>>(cmb, wto, b_out, out);
}

// Round 17
// 196.331 us; speedup vs baseline: 1.0553x; 1.0553x over previous
//
#include <hip/hip_runtime.h>
#include <math.h>

// Problem constants
#define B_     16
#define CIN_   128
#define NTOK_  640     // channels after concat = tokens
#define PSP_   256     // 16*16 spatial = token dim
#define EMB_   256
#define HEADS_ 8
#define DH_    32
#define BH_    128     // B_*HEADS_
#define NH_    8       // hashes
#define NBK_   10      // buckets per hash (t/BUCKET)
#define NC_    80      // chunks = NH_*NBK_
#define TOTROWS_ 10240 // B_*NTOK_
#define SORTLEN_ 5120  // NH_*NTOK_
#define VSTRIDE 136    // sVT row stride in shorts (272B: breaks the 256B bank period)

typedef __attribute__((ext_vector_type(8))) short short8;
typedef __attribute__((ext_vector_type(4))) short short4v;
typedef __attribute__((ext_vector_type(4))) float f32x4;

__device__ __forceinline__ unsigned bf16r(float f) {
  // round-to-nearest (half-up) fp32 -> bf16 bits
  return (__float_as_uint(f) + 0x8000u) >> 16;
}

__device__ __forceinline__ unsigned cvt_pk_bf16(float a, float b) {
  // packed fp32 -> 2x bf16 (lo = a, hi = b), RNE
  unsigned r;
  asm("v_cvt_pk_bf16_f32 %0, %1, %2" : "=v"(r) : "v"(a), "v"(b));
  return r;
}

// ---------------------------------------------------------------------------
// Kernel 1: maxpool(3,s2,p1) + Haar DWT -> tokens (B, 640, 256)
// + fused weight transpose/bf16 prep (blocks 0..255): wtv, wto
// ---------------------------------------------------------------------------
__global__ __launch_bounds__(256) void k_tokens(const float* __restrict__ x,
                                                float* __restrict__ tok,
                                                const float* __restrict__ wv,
                                                const float* __restrict__ wo,
                                                unsigned short* __restrict__ wtv,
                                                unsigned short* __restrict__ wto) {
  if (blockIdx.x < 256) {                       // fused k_prep
    int idx = blockIdx.x * 256 + threadIdx.x;   // 65536
    int n = idx >> 8, k = idx & 255;
    wtv[idx] = (unsigned short)bf16r(wv[k * 256 + n]);
    wto[idx] = (unsigned short)bf16r(wo[k * 256 + n]);
  }
  int tid = blockIdx.x * 256 + threadIdx.x;     // [0, 16*128*256)
  int p  = tid & 255;
  int bc = tid >> 8;                            // b*128 + c
  int i = p >> 4, j = p & 15;
  const float* xp = x + (size_t)bc * 1024;      // 32*32 plane
  int r0 = i * 2, c0 = j * 2;

  float mx = -3.4e38f;
  #pragma unroll
  for (int dr = -1; dr <= 1; dr++) {
    int r = r0 + dr;
    if (r < 0 || r >= 32) continue;
    #pragma unroll
    for (int dc = -1; dc <= 1; dc++) {
      int cc = c0 + dc;
      if (cc < 0 || cc >= 32) continue;
      mx = fmaxf(mx, xp[r * 32 + cc]);
    }
  }
  float a  = xp[r0 * 32 + c0];
  float bv = xp[r0 * 32 + c0 + 1];
  float cv = xp[(r0 + 1) * 32 + c0];
  float dv = xp[(r0 + 1) * 32 + c0 + 1];
  float ll = (a + bv + cv + dv) * 0.5f;
  float lh = (a - bv + cv - dv) * 0.5f;
  float hl = (a + bv - cv - dv) * 0.5f;
  float hh = (a - bv - cv + dv) * 0.5f;

  int b = bc >> 7, c = bc & 127;
  float* tb = tok + (size_t)b * NTOK_ * PSP_ + p;
  tb[(size_t)(c      ) * PSP_] = mx;
  tb[(size_t)(c + 128) * PSP_] = ll;
  tb[(size_t)(c + 256) * PSP_] = lh;
  tb[(size_t)(c + 384) * PSP_] = hl;
  tb[(size_t)(c + 512) * PSP_] = hh;
}

// ---------------------------------------------------------------------------
// Kernel 2: MERGED GEMM. Blocks 0..639: fp32 qk (argmax needs fp32) with
// dual fp32+bf16 output, 64x64 tile, BK=64. Blocks 640..959: bf16 MFMA
// v-GEMM (64 rows x 128 cols, 4 waves), bf16 output.
// ---------------------------------------------------------------------------
__global__ __launch_bounds__(256) void k_gemm_qv(const float* __restrict__ A,
                                                 const float* __restrict__ Wq,
                                                 const unsigned short* __restrict__ WTv,
                                                 float* __restrict__ C,
                                                 unsigned short* __restrict__ Cb,
                                                 unsigned short* __restrict__ Cv) {
  __shared__ float As[64][68];    // [k][row], padded +4
  __shared__ float Bs[64][64];    // [k][col]
  int tid = threadIdx.x;

  if (blockIdx.x < 640) {
    // ---------------- fp32 qk path ----------------
    int bx = blockIdx.x;
    int row0 = (bx >> 2) * 64, col0 = (bx & 3) * 64;
    int tx = tid & 15, ty = tid >> 4;
    float acc[4][4] = {};

    int lrow = tid >> 2, lkq = tid & 3;        // A loader
    int bkr = tid >> 4, bcq = tid & 15;        // B loader

    for (int k0 = 0; k0 < 256; k0 += 64) {
      float4 va[4], vb4[4];
      #pragma unroll
      for (int i = 0; i < 4; i++) {
        va[i]  = *(const float4*)(&A[(size_t)(row0 + lrow) * 256 + k0 + i * 16 + 4 * lkq]);
        vb4[i] = *(const float4*)(&Wq[(size_t)(k0 + i * 16 + bkr) * 256 + col0 + 4 * bcq]);
      }
      __syncthreads();
      #pragma unroll
      for (int i = 0; i < 4; i++) {
        As[i * 16 + 4 * lkq + 0][lrow] = va[i].x;
        As[i * 16 + 4 * lkq + 1][lrow] = va[i].y;
        As[i * 16 + 4 * lkq + 2][lrow] = va[i].z;
        As[i * 16 + 4 * lkq + 3][lrow] = va[i].w;
        *(float4*)(&Bs[i * 16 + bkr][4 * bcq]) = vb4[i];
      }
      __syncthreads();
      #pragma unroll
      for (int k = 0; k < 64; k++) {
        const float4 b4 = *(const float4*)(&Bs[k][4 * tx]);
        const float4 a4 = *(const float4*)(&As[k][4 * ty]);
        float ar[4] = {a4.x, a4.y, a4.z, a4.w};
        #pragma unroll
        for (int r = 0; r < 4; r++) {
          acc[r][0] += ar[r] * b4.x; acc[r][1] += ar[r] * b4.y;
          acc[r][2] += ar[r] * b4.z; acc[r][3] += ar[r] * b4.w;
        }
      }
    }
    #pragma unroll
    for (int r = 0; r < 4; r++) {
      float4 o;
      o.x = acc[r][0]; o.y = acc[r][1]; o.z = acc[r][2]; o.w = acc[r][3];
      size_t off = (size_t)(row0 + 4 * ty + r) * 256 + col0 + 4 * tx;
      *(float4*)(&C[off]) = o;
      uint2 ub;
      ub.x = bf16r(o.x) | (bf16r(o.y) << 16);
      ub.y = bf16r(o.z) | (bf16r(o.w) << 16);
      *(uint2*)(&Cb[off]) = ub;
    }
  } else {
    // ---------------- bf16 MFMA v path ----------------
    int vbk = blockIdx.x - 640;                // 0..319
    int wid = tid >> 6, lane = tid & 63;
    int lane15 = lane & 15, quad = lane >> 4;
    int row0 = (vbk >> 1) * 64 + wid * 16;
    int col0 = (vbk & 1) * 128;

    short8 fa[8];
    const float* arow = A + (size_t)(row0 + lane15) * 256;
    #pragma unroll
    for (int kc = 0; kc < 8; kc++) {
      float4 x0 = *(const float4*)(arow + kc * 32 + quad * 8);
      float4 x1 = *(const float4*)(arow + kc * 32 + quad * 8 + 4);
      short8 f;
      f[0] = (short)bf16r(x0.x); f[1] = (short)bf16r(x0.y);
      f[2] = (short)bf16r(x0.z); f[3] = (short)bf16r(x0.w);
      f[4] = (short)bf16r(x1.x); f[5] = (short)bf16r(x1.y);
      f[6] = (short)bf16r(x1.z); f[7] = (short)bf16r(x1.w);
      fa[kc] = f;
    }
    #pragma unroll
    for (int nt = 0; nt < 8; nt++) {
      int col = col0 + nt * 16 + lane15;
      f32x4 acc = {0.f, 0.f, 0.f, 0.f};
      const unsigned short* wrow = WTv + (size_t)col * 256;
      #pragma unroll
      for (int kc = 0; kc < 8; kc++) {
        short8 fb = *(const short8*)(wrow + kc * 32 + quad * 8);
        acc = __builtin_amdgcn_mfma_f32_16x16x32_bf16(fa[kc], fb, acc, 0, 0, 0);
      }
      #pragma unroll
      for (int rg = 0; rg < 4; rg++)
        Cv[(size_t)(row0 + 4 * quad + rg) * 256 + col] = (unsigned short)bf16r(acc[rg]);
    }
  }
}

// ---------------------------------------------------------------------------
// Kernel 3: LSH bucket + stable counting sort.
// XCD-SWIZZLED grid (128 bh, 8 hashes): bh = blockIdx.x so all 8 hash-blocks
// of one bh land on XCD bh%8 -> shared qk slice stays L2-resident.
// h==0 blocks additionally write nrmv[bh][t] = |qk row| (fp32) for k_attn.
// ---------------------------------------------------------------------------
__global__ __launch_bounds__(640) void k_sort(const float* __restrict__ qkg,
                                              const float* __restrict__ rot,
                                              int* __restrict__ st,
                                              float* __restrict__ nrmv) {
  int bh = blockIdx.x, h = blockIdx.y;
  int b = bh >> 3, head = bh & 7;
  __shared__ float srot[5][32];
  __shared__ int wcnt[10][10];   // [wave][bucket]
  __shared__ int woff[10][10];   // exclusive prefix over waves, per bucket
  __shared__ int gbase[10];      // exclusive prefix over buckets
  int tid = threadIdx.x, wv = tid >> 6, ln = tid & 63;

  if (tid < 160) {
    int i = tid >> 5, f = tid & 31;
    srot[i][f] = rot[f * (NH_ * 5) + h * 5 + i];   // rotations (32, 8, 5)
  }
  __syncthreads();

  int t = tid;                                     // one token per thread
  const float* qr = qkg + ((size_t)b * NTOK_ + t) * EMB_ + head * DH_;
  float q[32];
  #pragma unroll
  for (int d4 = 0; d4 < 8; d4++) {
    float4 f = *(const float4*)(qr + d4 * 4);
    q[d4 * 4 + 0] = f.x; q[d4 * 4 + 1] = f.y; q[d4 * 4 + 2] = f.z; q[d4 * 4 + 3] = f.w;
  }
  if (h == 0) {                                    // norm precompute for k_attn
    float d2 = 0.f;
    #pragma unroll
    for (int dd = 0; dd < 32; dd++) d2 += q[dd] * q[dd];
    nrmv[(size_t)bh * NTOK_ + t] = sqrtf(d2);
  }
  float r[5];
  #pragma unroll
  for (int i = 0; i < 5; i++) {
    float d = 0.f;
    #pragma unroll
    for (int dd = 0; dd < 32; dd++) d += q[dd] * srot[i][dd];
    r[i] = d;
  }
  int bi = 0; float best = r[0];
  #pragma unroll
  for (int i = 1; i < 5; i++) if (r[i] > best) { best = r[i]; bi = i; }
  #pragma unroll
  for (int i = 0; i < 5; i++) if (-r[i] > best) { best = -r[i]; bi = 5 + i; }

  // per-wave histogram + intra-wave stable rank via ballot
  int myoff = 0;
  #pragma unroll
  for (int kb = 0; kb < 10; kb++) {
    unsigned long long mask = __ballot(bi == kb);
    if (ln == 0) wcnt[wv][kb] = (int)__popcll(mask);
    if (bi == kb) myoff = (int)__popcll(mask & ((1ull << ln) - 1ull));
  }
  __syncthreads();
  if (tid < 10) {                                  // bucket = tid: scan over 10 waves
    int run = 0;
    #pragma unroll
    for (int w2 = 0; w2 < 10; w2++) { int tmp = wcnt[w2][tid]; woff[w2][tid] = run; run += tmp; }
    gbase[tid] = run;
  }
  __syncthreads();
  if (tid == 0) {
    int run = 0;
    #pragma unroll
    for (int kb = 0; kb < 10; kb++) { int tmp = gbase[kb]; gbase[kb] = run; run += tmp; }
  }
  __syncthreads();
  int rank = gbase[bi] + woff[wv][bi] + myoff;
  size_t gb = (size_t)bh * SORTLEN_ + (size_t)h * 640;
  st[gb + rank] = t;
}

// ---------------------------------------------------------------------------
// Kernel 4: MFMA chunked attention (R14-verified, best measured config).
// Single launch, grid (128 bh, 80 chunks). Unified staging (one st gather,
// 2 lanes/slot), swapped QK^T, in-register P, conflict-free V writes,
// positional self-mask for strips 0,1, token compare for strips 2,3.
// R15's chunk-chaining REVERTED: it collapsed occupancy (44->29.5%) and
// doubled bank conflicts; staging latency was already hidden by block TLP.
// ---------------------------------------------------------------------------
__global__ __launch_bounds__(256) void k_attn(const unsigned short* __restrict__ qkb,
                                              const unsigned short* __restrict__ vb,
                                              const int* __restrict__ st,
                                              const float* __restrict__ nrmv,
                                              unsigned short* __restrict__ osort,
                                              float* __restrict__ lseg) {
  __shared__ __attribute__((aligned(16))) short sK[4096];          // 128x32 bf16 RAW, pair-row swizzled
  __shared__ __attribute__((aligned(16))) short sVT[32 * VSTRIDE]; // 32 feats x 128 key-slots (PERMUTED), stride 136
  __shared__ __attribute__((aligned(16))) short sP[2048];          // 64x32 dense output staging
  __shared__ float sM[64];    // |q|*scale per query row
  __shared__ float sIK[128];  // LOG2E*scale/max(|k|,1e-6) per key (staged order)
  __shared__ float sL[64];    // row softmax denominators
  __shared__ int   stkv[128];

  const float scale = 0.17677669529663687f;   // 1/sqrt(32)
  const float LOG2E = 1.4426950408889634f;
  const float K2 = scale * LOG2E;
  int bh = blockIdx.x, c = blockIdx.y;
  int b = bh >> 3, head = bh & 7;
  int lane = threadIdx.x & 63, wid = threadIdx.x >> 6;   // wid 0..3
  size_t stb = (size_t)bh * SORTLEN_;
  int pcv = (c + NC_ - 1) % NC_;

  // ---- unified staging: one slot + one half per lane, ONE st gather ----
  {
    int slot = threadIdx.x & 127;              // kv slot
    int hf   = threadIdx.x >> 7;               // half-row (uniform per wave)
    int p0 = (slot < 64) ? (c * 64 + slot) : (pcv * 64 + (slot - 64));
    int t0 = st[stb + p0];
    size_t rowoff = ((size_t)(b * NTOK_ + t0)) * EMB_ + head * DH_;

    // K half-row: raw swizzled copy
    const uint4* kr = (const uint4*)(qkb + rowoff);
    uint4 ka = kr[2 * hf], kb2 = kr[2 * hf + 1];
    int pr = slot >> 1;
    int blk0 = ((slot & 1) << 2) | (2 * hf);
    *(uint4*)(&sK[pr * 64 + (((blk0    ) ^ (pr & 7)) << 3)]) = ka;
    *(uint4*)(&sK[pr * 64 + (((blk0 + 1) ^ (pr & 7)) << 3)]) = kb2;
    if (hf == 0) {
      stkv[slot] = t0;
      float nr = nrmv[(size_t)bh * NTOK_ + t0];
      if (slot < 64) sM[slot] = nr * scale;    // slots 0..63 are the queries
      sIK[slot] = K2 / fmaxf(nr, 1e-6f);
    }

    // V half-row: permuted slot, conflict-free b16 writes
    const uint4* vr = (const uint4*)(vb + rowoff);
    uint4 va = vr[2 * hf], vb4 = vr[2 * hf + 1];
    unsigned uw[8] = {va.x, va.y, va.z, va.w, vb4.x, vb4.y, vb4.z, vb4.w};
    int vslot = (slot & 96) | (((slot & 15) >> 2) << 3) | (((slot >> 4) & 1) << 2) | (slot & 3);
    short* vbase = &sVT[hf * 16 * VSTRIDE + vslot];
    #pragma unroll
    for (int j = 0; j < 16; j++) {             // feat = 16*hf + j; imm offsets
      unsigned s = (j & 1) ? (uw[j >> 1] >> 16) : uw[j >> 1];
      vbase[j * VSTRIDE] = (short)s;
    }
  }
  __syncthreads();

  int lane15 = lane & 15, quad = lane >> 4;

  short8 fall[8];                              // all raw-K frags (static idx)
  #pragma unroll
  for (int i = 0; i < 8; i++) {
    int key = 16 * i + lane15, pr = key >> 1;
    int blk = ((key & 1) << 2) | quad;
    fall[i] = *(const short8*)(&sK[pr * 64 + ((blk ^ (pr & 7)) << 3)]);
  }
  short8 fq;                                   // this wave's raw-Q frag: wid in ADDRESS
  {
    int row = 16 * wid + lane15, pr = row >> 1;
    int blk = ((row & 1) << 2) | quad;
    fq = *(const short8*)(&sK[pr * 64 + ((blk ^ (pr & 7)) << 3)]);
  }

  // per-lane softmax state: this lane's query is slot 16*wid + lane15
  int   tq  = stkv[16 * wid + lane15];
  float mq  = sM[16 * wid + lane15];
  float mq2 = mq * LOG2E;
  int   qd  = 16 * wid + lane15 - 4 * quad;    // strips 0,1: diag iff qd == 32s+16ct+rg

  f32x4 O[2];
  #pragma unroll
  for (int vt = 0; vt < 2; vt++) { O[vt][0]=0.f; O[vt][1]=0.f; O[vt][2]=0.f; O[vt][3]=0.f; }
  float lacc = 0.f;

  #pragma unroll                               // FULL UNROLL: static reg indices
  for (int s = 0; s < 4; s++) {                // 4 key strips of 32
    f32x4 z = {0.f, 0.f, 0.f, 0.f};
    f32x4 Sv[2];
    #pragma unroll
    for (int ct = 0; ct < 2; ct++)             // SWAPPED: A=K, B=Q -> col=query, row=key
      Sv[ct] = __builtin_amdgcn_mfma_f32_16x16x32_bf16(fall[2 * s + ct], fq, z, 0, 0, 0);

    unsigned pk[2][2];
    #pragma unroll
    for (int ct = 0; ct < 2; ct++) {
      // keys 32s+16ct+4quad .. +3 (staged order)
      const float4 c4 = *(const float4*)(&sIK[32 * s + 16 * ct + 4 * quad]);
      float cc[4] = {c4.x, c4.y, c4.z, c4.w};
      int kk[4];
      if (s >= 2) {                            // prev-chunk strips: token ids
        const int4 k4 = *(const int4*)(&stkv[32 * s + 16 * ct + 4 * quad]);
        kk[0] = k4.x; kk[1] = k4.y; kk[2] = k4.z; kk[3] = k4.w;
      }
      float e[4];
      #pragma unroll
      for (int rg = 0; rg < 4; rg++) {
        float v = __builtin_exp2f(__builtin_fmaf(Sv[ct][rg], cc[rg], -mq2));
        if (s < 2) {                           // current chunk: positional diagonal
          if (qd == 32 * s + 16 * ct + rg) v = 0.f;
        } else {                               // prev chunk: token compare (exact)
          if (kk[rg] == tq) v = 0.f;
        }
        lacc += v;
        e[rg] = v;
      }
      pk[ct][0] = cvt_pk_bf16(e[0], e[1]);
      pk[ct][1] = cvt_pk_bf16(e[2], e[3]);
    }
    short8 fp;                                 // A-frag: keys in lane-owned order
    {
      union { unsigned u[4]; short8 v; } cv_;
      cv_.u[0] = pk[0][0]; cv_.u[1] = pk[0][1];
      cv_.u[2] = pk[1][0]; cv_.u[3] = pk[1][1];
      fp = cv_.v;
    }
    short8 fv[2];
    #pragma unroll
    for (int vt = 0; vt < 2; vt++)             // permuted slots match fp's key order
      fv[vt] = *(const short8*)(&sVT[(16 * vt + lane15) * VSTRIDE + 32 * s + (quad << 3)]);
    #pragma unroll
    for (int vt = 0; vt < 2; vt++)
      O[vt] = __builtin_amdgcn_mfma_f32_16x16x32_bf16(fp, fv[vt], O[vt], 0, 0, 0);
  }

  // row sum: reduce over the 4 quads holding this query's keys
  lacc += __shfl_xor(lacc, 16);
  lacc += __shfl_xor(lacc, 32);

  int h = c / NBK_;  // hash round of this chunk
  if (lane < 16) {                             // one lane per query row
    sL[16 * wid + lane] = lacc;
    lseg[((size_t)bh * NTOK_ + tq) * NH_ + h] = mq + __logf(lacc);
  }
  float4 lr = *(const float4*)(&sL[16 * wid + 4 * quad]);  // same-wave LDS dep
  float lrow[4] = {lr.x, lr.y, lr.z, lr.w};
  #pragma unroll
  for (int rg = 0; rg < 4; rg++) {
    float invl = 1.f / lrow[rg];
    #pragma unroll
    for (int vt = 0; vt < 2; vt++) {
      float o = O[vt][rg] * invl;
      sP[(16 * wid + 4 * quad + rg) * 32 + 16 * vt + lane15] = (short)bf16r(o);
    }
  }
  __syncthreads();
  // scatter bf16 O by original time: osort[bh][t][h][32]
  {
    int row = threadIdx.x >> 2, seg = threadIdx.x & 3;
    int t = stkv[row];
    uint4* dst = (uint4*)(osort + (((size_t)bh * NTOK_ + t) * NH_ + h) * 32 + seg * 8);
    *dst = ((const uint4*)sP)[threadIdx.x];
  }
}

// ---------------------------------------------------------------------------
// Kernel 5a: combine 8 hash rounds -> cmb[b*640+t][256] bf16.
// grid 1280 x 256: 4 threads per (bh,t), each handles 8 features (1 uint4/h).
// ---------------------------------------------------------------------------
__global__ __launch_bounds__(256) void k_combine(const unsigned short* __restrict__ osort,
                                                 const float* __restrict__ lseg,
                                                 unsigned short* __restrict__ cmb) {
  int g = blockIdx.x * 256 + threadIdx.x;      // 327,680 = 81,920 tasks x 4
  int part = g & 3;
  int task = g >> 2;                           // bh*640 + t
  int bh = task / 640;
  int t  = task - bh * 640;
  size_t base = (size_t)task;

  float l[8];
  float4 l0 = *(const float4*)(lseg + base * 8);
  float4 l1 = *(const float4*)(lseg + base * 8 + 4);
  l[0]=l0.x; l[1]=l0.y; l[2]=l0.z; l[3]=l0.w;
  l[4]=l1.x; l[5]=l1.y; l[6]=l1.z; l[7]=l1.w;
  float m = -3.4e38f;
  #pragma unroll
  for (int h = 0; h < 8; h++) m = fmaxf(m, l[h]);
  float ssum = 0.f;
  #pragma unroll
  for (int h = 0; h < 8; h++) { l[h] = __expf(l[h] - m); ssum += l[h]; }
  float inv = 1.0f / ssum;

  float acc[8] = {};
  const uint4* orows = (const uint4*)osort;
  size_t obase = base * 32 + part;             // uint4 index: (base*8+h)*4 + part
  #pragma unroll
  for (int h = 0; h < 8; h++) {
    float w = l[h] * inv;
    uint4 u = orows[obase + h * 4];
    unsigned uu[4] = {u.x, u.y, u.z, u.w};
    #pragma unroll
    for (int q2 = 0; q2 < 4; q2++) {
      float lo = __uint_as_float(uu[q2] << 16);
      float hi = __uint_as_float(uu[q2] & 0xFFFF0000u);
      acc[q2 * 2 + 0] += w * lo;
      acc[q2 * 2 + 1] += w * hi;
    }
  }
  int b = bh >> 3, head = bh & 7;
  uint4 o;
  o.x = bf16r(acc[0]) | (bf16r(acc[1]) << 16);
  o.y = bf16r(acc[2]) | (bf16r(acc[3]) << 16);
  o.z = bf16r(acc[4]) | (bf16r(acc[5]) << 16);
  o.w = bf16r(acc[6]) | (bf16r(acc[7]) << 16);
  *(uint4*)(cmb + ((size_t)(b * NTOK_ + t)) * 256 + head * 32 + part * 8) = o;
}

// ---------------------------------------------------------------------------
// Kernel 5b: output projection, pure bf16 MFMA GEMM 10240x256x256 + bias.
// grid 640: 16-row tiles; 4 waves = 4 col-quarters of 64. No LDS.
// ---------------------------------------------------------------------------
__global__ __launch_bounds__(256) void k_oproj(const unsigned short* __restrict__ cmb,
                                               const unsigned short* __restrict__ WT,
                                               const float* __restrict__ bias,
                                               float* __restrict__ C) {
  int rt = blockIdx.x;                         // 0..639: rows rt*16..+15
  int tid = threadIdx.x;
  int wid = tid >> 6, lane = tid & 63;
  int lane15 = lane & 15, quad = lane >> 4;
  int row0 = rt * 16;
  int col0 = wid * 64;

  short8 fa[8];
  const unsigned short* arow = cmb + (size_t)(row0 + lane15) * 256;
  #pragma unroll
  for (int kc = 0; kc < 8; kc++)
    fa[kc] = *(const short8*)(arow + kc * 32 + quad * 8);
  #pragma unroll
  for (int nt = 0; nt < 4; nt++) {
    int col = col0 + nt * 16 + lane15;
    f32x4 acc = {0.f, 0.f, 0.f, 0.f};
    const unsigned short* wrow = WT + (size_t)col * 256;
    #pragma unroll
    for (int kc = 0; kc < 8; kc++) {
      short8 fb = *(const short8*)(wrow + kc * 32 + quad * 8);
      acc = __builtin_amdgcn_mfma_f32_16x16x32_bf16(fa[kc], fb, acc, 0, 0, 0);
    }
    float bb = bias[col];
    #pragma unroll
    for (int rg = 0; rg < 4; rg++)
      C[(size_t)(row0 + 4 * quad + rg) * 256 + col] = acc[rg] + bb;
  }
}

// ---------------------------------------------------------------------------
extern "C" void kernel_launch(void* const* d_in, const int* in_sizes, int n_in,
                              void* d_out, int out_size, void* d_ws, size_t ws_size,
                              hipStream_t stream) {
  const float* x     = (const float*)d_in[0];
  const float* w_qk  = (const float*)d_in[1];
  const float* w_v   = (const float*)d_in[2];
  const float* w_out = (const float*)d_in[3];
  const float* b_out = (const float*)d_in[4];
  const float* rot   = (const float*)d_in[5];
  float* out = (float*)d_out;

  // workspace layout (float units)
  float* tokens  = (float*)d_ws;                      // 2,621,440 f
  float* qk      = tokens + 2621440;                  // 2,621,440 f
  unsigned short* qkb = (unsigned short*)(qk + 2621440); // 2,621,440 bf16
  unsigned short* vbv = qkb + 2621440;                // 2,621,440 bf16
  int*   st      = (int*)(vbv + 2621440);             // 655,360
  float* lse     = (float*)(st + 655360);             // 655,360  [bh][t][h]
  unsigned short* osort = (unsigned short*)(lse + 655360);  // 20,971,520 bf16 [bh][t][h][32]
  unsigned short* wtv = osort + 20971520;             // 65,536 bf16 (W_v^T)
  unsigned short* wto = wtv + 65536;                  // 65,536 bf16 (W_out^T)
  // nrmv (81,920 f) aliases tokens (dead after k_gemm_qv).
  float* nrmv = tokens;
  // cmb (2,621,440 bf16 = 5.2 MB) aliases qk (dead after k_sort).
  unsigned short* cmb = (unsigned short*)qk;

  k_tokens<<<2048, 256, 0, stream>>>(x, tokens, w_v, w_out, wtv, wto);
  k_gemm_qv<<<960, 256, 0, stream>>>(tokens, w_qk, wtv, qk, qkb, vbv);
  k_sort<<<dim3(128, 8), 640, 0, stream>>>(qk, rot, st, nrmv);          // bh-major: XCD locality
  k_attn<<<dim3(128, 80), 256, 0, stream>>>(qkb, vbv, st, nrmv, osort, lse);
  k_combine<<<1280, 256, 0, stream>>>(osort, lse, cmb);
  k_oproj<<<640, 256, 0, stream>>>(cmb, wto, b_out, out);
}